// Round 2
// baseline (19170.889 us; speedup 1.0000x reference)
//
#include <hip/hip_runtime.h>
#include <math.h>

#define NTOK 8192
#define NEMB 8192
#define DIM  256
#define NSEG 8
#define ESEG (NEMB / NSEG)   // 1024 codes per segment
#define TM   128             // tokens per block
#define TE   128             // codes per e-tile
#define KT   32              // k-chunk staged in LDS

// ---------------------------------------------------------------------------
// Kernel 0: exact ||c||^2 per codebook row (fp32). 4 waves/block, 4 codes/wave.
__global__ __launch_bounds__(256) void cnorm_kernel(const float* __restrict__ C,
                                                    float* __restrict__ cnorm) {
    int w = blockIdx.x * 4 + (threadIdx.x >> 6);
    int lane = threadIdx.x & 63;
    #pragma unroll
    for (int i = 0; i < 4; ++i) {
        int e = w * 4 + i;
        float4 c = *(const float4*)&C[(size_t)e * DIM + lane * 4];
        float s = c.x * c.x + c.y * c.y + c.z * c.z + c.w * c.w;
        #pragma unroll
        for (int off = 32; off >= 1; off >>= 1) s += __shfl_xor(s, off);
        if (lane == 0) cnorm[e] = s;
    }
}

// ---------------------------------------------------------------------------
// Kernel 1: fused distance GEMM + per-segment argmin.
// Block: 256 threads as (tx 0..15, ty 0..15). Thread tile: 8 tokens x 8 codes.
// Block tile: 128 tokens x 128 codes, looping over a 1024-code segment.
// LDS float4 granules XOR-swizzled by (row>>3)&7 to break the 128B-row-stride
// bank aliasing. Register budget: acc 64 + b[8] 32 + a 4 + addr ~40 -> no
// spill under the 168-VGPR cap from __launch_bounds__(256,3).
__global__ __launch_bounds__(256, 3) void dist_argmin_kernel(
        const float* __restrict__ X, const float* __restrict__ C,
        const float* __restrict__ cnorm,
        float* __restrict__ seg_minv, int* __restrict__ seg_mini) {
    __shared__ float4 Xs[TM * (KT / 4)];   // [row][k4] swizzled, 16 KB
    __shared__ float4 Cs[TE * (KT / 4)];   // 16 KB

    const int t  = threadIdx.x;
    const int tx = t & 15, ty = t >> 4;
    const int m0 = blockIdx.x * TM;
    const int seg = blockIdx.y;
    const int e0 = seg * ESEG;

    float minv[8];
    int   mini[8];
    #pragma unroll
    for (int j = 0; j < 8; ++j) { minv[j] = 1e30f; mini[j] = 0x7fffffff; }

    #pragma unroll 1
    for (int et = 0; et < ESEG / TE; ++et) {
        const int eb = e0 + et * TE;
        float acc[8][8];
        #pragma unroll
        for (int j = 0; j < 8; ++j)
            #pragma unroll
            for (int l = 0; l < 8; ++l) acc[j][l] = 0.0f;

        #pragma unroll 1
        for (int kt = 0; kt < DIM / KT; ++kt) {
            const int k0 = kt * KT;
            __syncthreads();
            const float* Xg = X + (size_t)m0 * DIM + k0;
            const float* Cg = C + (size_t)eb * DIM + k0;
            {
                int row = t >> 3, k4 = t & 7;           // f = t (rows 0..31)
                int sw = row * 8 + (k4 ^ ((row >> 3) & 7));
                Xs[sw]       = *(const float4*)(Xg + (size_t)row * DIM + k4 * 4);
                Xs[sw + 256] = *(const float4*)(Xg + (size_t)(row + 32) * DIM + k4 * 4);
                Xs[sw + 512] = *(const float4*)(Xg + (size_t)(row + 64) * DIM + k4 * 4);
                Xs[sw + 768] = *(const float4*)(Xg + (size_t)(row + 96) * DIM + k4 * 4);
                Cs[sw]       = *(const float4*)(Cg + (size_t)row * DIM + k4 * 4);
                Cs[sw + 256] = *(const float4*)(Cg + (size_t)(row + 32) * DIM + k4 * 4);
                Cs[sw + 512] = *(const float4*)(Cg + (size_t)(row + 64) * DIM + k4 * 4);
                Cs[sw + 768] = *(const float4*)(Cg + (size_t)(row + 96) * DIM + k4 * 4);
            }
            __syncthreads();

            #pragma unroll
            for (int k4 = 0; k4 < KT / 4; ++k4) {
                const int sa = k4 ^ (ty & 7);   // (ty*8+j)>>3 == ty for j<8
                const int sb = k4 ^ (tx & 7);
                float4 b[8];
                #pragma unroll
                for (int l = 0; l < 8; ++l) b[l] = Cs[(tx * 8 + l) * 8 + sb];
                #pragma unroll
                for (int j = 0; j < 8; ++j) {
                    float4 a = Xs[(ty * 8 + j) * 8 + sa];
                    #pragma unroll
                    for (int l = 0; l < 8; ++l) {
                        acc[j][l] += a.x * b[l].x + a.y * b[l].y
                                   + a.z * b[l].z + a.w * b[l].w;
                    }
                }
            }
        }

        // fold this e-tile into the running per-thread argmin
        float cn[8];
        {
            float4 c0 = *(const float4*)&cnorm[eb + tx * 8];
            float4 c1 = *(const float4*)&cnorm[eb + tx * 8 + 4];
            cn[0] = c0.x; cn[1] = c0.y; cn[2] = c0.z; cn[3] = c0.w;
            cn[4] = c1.x; cn[5] = c1.y; cn[6] = c1.z; cn[7] = c1.w;
        }
        #pragma unroll
        for (int j = 0; j < 8; ++j) {
            #pragma unroll
            for (int l = 0; l < 8; ++l) {
                float d = cn[l] - 2.0f * acc[j][l];   // ||c||^2 - 2 x.c
                int e = eb + tx * 8 + l;              // ascending -> strict <
                if (d < minv[j]) { minv[j] = d; mini[j] = e; }
            }
        }
    }

    // reduce across the 16 tx lanes (lanes [ty%4]*16 .. +15 within a wave)
    #pragma unroll
    for (int j = 0; j < 8; ++j) {
        float v = minv[j]; int bi = mini[j];
        #pragma unroll
        for (int off = 8; off >= 1; off >>= 1) {
            float ov = __shfl_xor(v, off);
            int   oi = __shfl_xor(bi, off);
            if (ov < v || (ov == v && oi < bi)) { v = ov; bi = oi; }
        }
        if (tx == 0) {
            int token = m0 + ty * 8 + j;
            seg_minv[(size_t)token * NSEG + seg] = v;
            seg_mini[(size_t)token * NSEG + seg] = bi;
        }
    }
}

// ---------------------------------------------------------------------------
// Kernel 2: fold the NSEG candidates per token; histogram.
__global__ __launch_bounds__(256) void reduce_idx_kernel(
        const float* __restrict__ seg_minv, const int* __restrict__ seg_mini,
        int* __restrict__ idx, int* __restrict__ counts) {
    int token = blockIdx.x * 256 + threadIdx.x;
    float bv = 1e30f; int bi = 0x7fffffff;
    #pragma unroll
    for (int s = 0; s < NSEG; ++s) {
        float v = seg_minv[(size_t)token * NSEG + s];
        int   i = seg_mini[(size_t)token * NSEG + s];
        if (v < bv || (v == bv && i < bi)) { bv = v; bi = i; }
    }
    idx[token] = bi;
    atomicAdd(&counts[bi], 1);
}

// ---------------------------------------------------------------------------
// Kernel 3: gather codebook rows -> out, accumulate sum((q-x)^2).
__global__ __launch_bounds__(256) void gather_loss_kernel(
        const float* __restrict__ X, const float* __restrict__ C,
        const int* __restrict__ idx, float* __restrict__ out,
        float* __restrict__ sumsq) {
    int wave = blockIdx.x * 4 + (threadIdx.x >> 6);
    int lane = threadIdx.x & 63;
    float local = 0.0f;
    #pragma unroll
    for (int i = 0; i < 2; ++i) {
        int token = wave * 2 + i;
        int e = idx[token];
        float4 q = *(const float4*)&C[(size_t)e * DIM + lane * 4];
        float4 x = *(const float4*)&X[(size_t)token * DIM + lane * 4];
        *(float4*)&out[(size_t)token * DIM + lane * 4] = q;
        float d0 = q.x - x.x, d1 = q.y - x.y, d2 = q.z - x.z, d3 = q.w - x.w;
        local += d0 * d0 + d1 * d1 + d2 * d2 + d3 * d3;
    }
    #pragma unroll
    for (int off = 32; off >= 1; off >>= 1) local += __shfl_xor(local, off);
    if (lane == 0) atomicAdd(sumsq, local);
}

// ---------------------------------------------------------------------------
// Kernel 4: loss + perplexity scalars.
__global__ __launch_bounds__(256) void finalize_kernel(
        const int* __restrict__ counts, const float* __restrict__ sumsq,
        float* __restrict__ out) {
    double local = 0.0;
    for (int e = threadIdx.x; e < NEMB; e += 256) {
        float p = (float)counts[e] * (1.0f / (float)NTOK);
        local += (double)(p * logf(p + 1e-10f));
    }
    #pragma unroll
    for (int off = 32; off >= 1; off >>= 1) local += __shfl_xor(local, off);
    __shared__ double sh[4];
    int lane = threadIdx.x & 63, wid = threadIdx.x >> 6;
    if (lane == 0) sh[wid] = local;
    __syncthreads();
    if (threadIdx.x == 0) {
        double tot = sh[0] + sh[1] + sh[2] + sh[3];
        out[(size_t)NTOK * DIM]     = 1.25f * sumsq[0] / (float)((size_t)NTOK * DIM);
        out[(size_t)NTOK * DIM + 1] = expf((float)(-tot));
    }
}

// ---------------------------------------------------------------------------
extern "C" void kernel_launch(void* const* d_in, const int* in_sizes, int n_in,
                              void* d_out, int out_size, void* d_ws, size_t ws_size,
                              hipStream_t stream) {
    const float* X = (const float*)d_in[0];   // [32,256,256] fp32
    const float* C = (const float*)d_in[1];   // [8192,256]   fp32
    float* out = (float*)d_out;               // 2097152 + 2 fp32

    char* ws = (char*)d_ws;
    float* cnorm    = (float*)(ws);                                  // 32 KB
    float* seg_minv = (float*)(ws + 32768);                          // 256 KB
    int*   seg_mini = (int*)  (ws + 32768 + 262144);                 // 256 KB
    int*   idx      = (int*)  (ws + 32768 + 262144 + 262144);        // 32 KB
    int*   counts   = (int*)  (ws + 32768 + 262144 + 262144 + 32768);// 32 KB
    float* sumsq    = (float*)(ws + 32768 + 262144 + 262144 + 32768 + 32768);

    hipMemsetAsync(counts, 0, NEMB * sizeof(int) + sizeof(float), stream);

    cnorm_kernel<<<NEMB / 16, 256, 0, stream>>>(C, cnorm);
    dist_argmin_kernel<<<dim3(NTOK / TM, NSEG), 256, 0, stream>>>(
        X, C, cnorm, seg_minv, seg_mini);
    reduce_idx_kernel<<<NTOK / 256, 256, 0, stream>>>(seg_minv, seg_mini, idx, counts);
    gather_loss_kernel<<<NTOK / 8, 256, 0, stream>>>(X, C, idx, out, sumsq);
    finalize_kernel<<<1, 256, 0, stream>>>(counts, sumsq, out);
}

// Round 3
// 333.730 us; speedup vs baseline: 57.4444x; 57.4444x over previous
//
#include <hip/hip_runtime.h>
#include <math.h>

#define NTOK 8192
#define NEMB 8192
#define DIM  256
#define NPB  64            // partial-candidate sets per token (= grid.y of GEMM)

typedef __attribute__((ext_vector_type(8))) short bf16x8;   // 8 bf16 = 4 VGPRs
typedef __attribute__((ext_vector_type(4))) float f32x4;

__device__ inline unsigned short f2bf(float f) {            // RNE fp32->bf16
    unsigned u = __builtin_bit_cast(unsigned, f);
    u = (u + 0x7fffu + ((u >> 16) & 1u)) >> 16;
    return (unsigned short)u;
}
__device__ inline float bf2f(unsigned short b) {
    unsigned u = (unsigned)b << 16;
    return __builtin_bit_cast(float, u);
}

// ---------------------------------------------------------------------------
// Kernel A: split X and C into bf16 hi/lo pairs. blockIdx.y: 0 = X, 1 = C.
__global__ __launch_bounds__(256) void convert_kernel(
        const float* __restrict__ X, const float* __restrict__ C,
        unsigned short* __restrict__ Xhi, unsigned short* __restrict__ Xlo,
        unsigned short* __restrict__ Chi, unsigned short* __restrict__ Clo) {
    const float* src = blockIdx.y ? C : X;
    unsigned short* hi = blockIdx.y ? Chi : Xhi;
    unsigned short* lo = blockIdx.y ? Clo : Xlo;
    size_t t = (size_t)blockIdx.x * 256 + threadIdx.x;   // one float4 per thread
    float4 x = *(const float4*)&src[t * 4];
    ushort4 h, l;
    h.x = f2bf(x.x); l.x = f2bf(x.x - bf2f(h.x));
    h.y = f2bf(x.y); l.y = f2bf(x.y - bf2f(h.y));
    h.z = f2bf(x.z); l.z = f2bf(x.z - bf2f(h.z));
    h.w = f2bf(x.w); l.w = f2bf(x.w - bf2f(h.w));
    *(ushort4*)&hi[t * 4] = h;
    *(ushort4*)&lo[t * 4] = l;
}

// ---------------------------------------------------------------------------
// Kernel B: exact fp32 ||c||^2 per codebook row.
__global__ __launch_bounds__(256) void cnorm_kernel(const float* __restrict__ C,
                                                    float* __restrict__ cnorm) {
    int w = blockIdx.x * 4 + (threadIdx.x >> 6);
    int lane = threadIdx.x & 63;
    #pragma unroll
    for (int i = 0; i < 4; ++i) {
        int e = w * 4 + i;
        float4 c = *(const float4*)&C[(size_t)e * DIM + lane * 4];
        float s = c.x * c.x + c.y * c.y + c.z * c.z + c.w * c.w;
        #pragma unroll
        for (int off = 32; off >= 1; off >>= 1) s += __shfl_xor(s, off);
        if (lane == 0) cnorm[e] = s;
    }
}

// ---------------------------------------------------------------------------
// Kernel C: bf16-split distance GEMM (K=768 effective) + fused argmin.
// Grid (64 m-blocks, 64 n-blocks), 256 threads = 4 waves in 2x2, each wave a
// 64x64 quadrant as 4x4 MFMA 16x16x32 tiles. LDS: 16B granules at
// [row][kg ^ (row&7)] — XOR swizzle keeps frag ds_read_b128 at 2-way (free)
// and is exactly lane-contiguous for global_load_lds width-16 staging.
__global__ __launch_bounds__(256) void mfma_argmin_kernel(
        const unsigned short* __restrict__ Xhi, const unsigned short* __restrict__ Xlo,
        const unsigned short* __restrict__ Chi, const unsigned short* __restrict__ Clo,
        const float* __restrict__ cnorm,
        float* __restrict__ minv_p, int* __restrict__ mini_p) {
    __shared__ __align__(16) unsigned short A_lds[128 * 64];  // 16 KB
    __shared__ __align__(16) unsigned short B_lds[128 * 64];  // 16 KB
    __shared__ float cmb_v[128][2];
    __shared__ int   cmb_i[128][2];

    const int t = threadIdx.x;
    const int wid = t >> 6, lane = t & 63;
    const int bm = blockIdx.x, bn = blockIdx.y;
    const int m0 = bm * 128, n0 = bn * 128;
    const int wm = (wid >> 1) * 64, wn = (wid & 1) * 64;
    const int lrow = lane & 15;     // row-in-tile for A/B frags, col for C/D
    const int g = lane >> 4;        // quad

    f32x4 acc[4][4];                // [tm][tn]
    #pragma unroll
    for (int a = 0; a < 4; ++a)
        #pragma unroll
        for (int b = 0; b < 4; ++b) acc[a][b] = (f32x4)0.0f;

    // staging split: wid0 -> A granules 0..511, wid1 -> A 512..1023,
    //                wid2 -> B 0..511,          wid3 -> B 512..1023
    unsigned short* stage_lds = (wid < 2) ? A_lds : B_lds;
    const int gr_base = (wid & 1) * 512;

    #pragma unroll 1
    for (int kt = 0; kt < 12; ++kt) {
        // K-segment selection: dot = Xhi.Chi (kt 0-3) + Xhi.Clo (4-7) + Xlo.Chi (8-11)
        const unsigned short* Agl = (kt < 8) ? Xhi : Xlo;
        const unsigned short* Bgl = (kt >= 4 && kt < 8) ? Clo : Chi;
        const int col0 = (kt & 3) * 64;

        __syncthreads();
        {
            const unsigned short* gbase =
                (wid < 2) ? (Agl + (size_t)m0 * DIM) : (Bgl + (size_t)n0 * DIM);
            #pragma unroll
            for (int c = 0; c < 8; ++c) {
                int gr  = gr_base + c * 64 + lane;       // granule 0..1023
                int row = gr >> 3, kgp = gr & 7;
                int kg  = kgp ^ (row & 7);               // un-swizzle for global
                const unsigned short* gp = gbase + row * DIM + col0 + kg * 8;
                unsigned short* lp = stage_lds + (size_t)(gr_base + c * 64) * 8;
                __builtin_amdgcn_global_load_lds(
                    (const __attribute__((address_space(1))) void*)gp,
                    (__attribute__((address_space(3))) void*)lp, 16, 0, 0);
            }
        }
        __syncthreads();

        #pragma unroll
        for (int ks = 0; ks < 2; ++ks) {
            const int kg = ks * 4 + g;
            bf16x8 af[4], bf_[4];
            #pragma unroll
            for (int tm = 0; tm < 4; ++tm) {
                int row = wm + tm * 16 + lrow;
                af[tm] = *(const bf16x8*)&A_lds[(row * 8 + (kg ^ (row & 7))) * 8];
            }
            #pragma unroll
            for (int tn = 0; tn < 4; ++tn) {
                int row = wn + tn * 16 + lrow;
                bf_[tn] = *(const bf16x8*)&B_lds[(row * 8 + (kg ^ (row & 7))) * 8];
            }
            #pragma unroll
            for (int tm = 0; tm < 4; ++tm)
                #pragma unroll
                for (int tn = 0; tn < 4; ++tn)
                    acc[tm][tn] = __builtin_amdgcn_mfma_f32_16x16x32_bf16(
                        af[tm], bf_[tn], acc[tm][tn], 0, 0, 0);
        }
    }

    // ---- fused argmin epilogue: d = ||c||^2 - 2 x.c ----
    float cn[4];
    #pragma unroll
    for (int tn = 0; tn < 4; ++tn) cn[tn] = cnorm[n0 + wn + tn * 16 + lrow];

    #pragma unroll
    for (int tm = 0; tm < 4; ++tm) {
        #pragma unroll
        for (int reg = 0; reg < 4; ++reg) {
            float v = 1e30f; int bi = 0x7fffffff;
            #pragma unroll
            for (int tn = 0; tn < 4; ++tn) {
                float d = cn[tn] - 2.0f * acc[tm][tn][reg];
                int e = n0 + wn + tn * 16 + lrow;
                if (d < v || (d == v && e < bi)) { v = d; bi = e; }
            }
            #pragma unroll
            for (int off = 1; off < 16; off <<= 1) {   // reduce over the 16 cols
                float ov = __shfl_xor(v, off);
                int   oi = __shfl_xor(bi, off);
                if (ov < v || (ov == v && oi < bi)) { v = ov; bi = oi; }
            }
            if (lrow == 0) {
                int r = wm + tm * 16 + g * 4 + reg;    // C/D: row = quad*4 + reg
                cmb_v[r][wid & 1] = v; cmb_i[r][wid & 1] = bi;
            }
        }
    }
    __syncthreads();
    if (t < 128) {
        float v0 = cmb_v[t][0], v1 = cmb_v[t][1];
        int   i0 = cmb_i[t][0], i1 = cmb_i[t][1];
        bool tk = (v1 < v0) || (v1 == v0 && i1 < i0);
        minv_p[(size_t)bn * NTOK + m0 + t] = tk ? v1 : v0;
        mini_p[(size_t)bn * NTOK + m0 + t] = tk ? i1 : i0;
    }
}

// ---------------------------------------------------------------------------
// Kernel D: fold the NPB candidates per token; histogram.
__global__ __launch_bounds__(256) void reduce_idx_kernel(
        const float* __restrict__ minv_p, const int* __restrict__ mini_p,
        int* __restrict__ idx, int* __restrict__ counts) {
    int token = blockIdx.x * 256 + threadIdx.x;
    float bv = 1e30f; int bi = 0x7fffffff;
    #pragma unroll 1
    for (int p = 0; p < NPB; ++p) {
        float v = minv_p[(size_t)p * NTOK + token];
        int   i = mini_p[(size_t)p * NTOK + token];
        if (v < bv || (v == bv && i < bi)) { bv = v; bi = i; }
    }
    idx[token] = bi;
    atomicAdd(&counts[bi], 1);
}

// ---------------------------------------------------------------------------
// Kernel E: gather codebook rows -> out, accumulate sum((q-x)^2).
__global__ __launch_bounds__(256) void gather_loss_kernel(
        const float* __restrict__ X, const float* __restrict__ C,
        const int* __restrict__ idx, float* __restrict__ out,
        float* __restrict__ sumsq) {
    int wave = blockIdx.x * 4 + (threadIdx.x >> 6);
    int lane = threadIdx.x & 63;
    float local = 0.0f;
    #pragma unroll
    for (int i = 0; i < 2; ++i) {
        int token = wave * 2 + i;
        int e = idx[token];
        float4 q = *(const float4*)&C[(size_t)e * DIM + lane * 4];
        float4 x = *(const float4*)&X[(size_t)token * DIM + lane * 4];
        *(float4*)&out[(size_t)token * DIM + lane * 4] = q;
        float d0 = q.x - x.x, d1 = q.y - x.y, d2 = q.z - x.z, d3 = q.w - x.w;
        local += d0 * d0 + d1 * d1 + d2 * d2 + d3 * d3;
    }
    #pragma unroll
    for (int off = 32; off >= 1; off >>= 1) local += __shfl_xor(local, off);
    if (lane == 0) atomicAdd(sumsq, local);
}

// ---------------------------------------------------------------------------
// Kernel F: loss + perplexity scalars.
__global__ __launch_bounds__(256) void finalize_kernel(
        const int* __restrict__ counts, const float* __restrict__ sumsq,
        float* __restrict__ out) {
    double local = 0.0;
    for (int e = threadIdx.x; e < NEMB; e += 256) {
        float p = (float)counts[e] * (1.0f / (float)NTOK);
        local += (double)(p * logf(p + 1e-10f));
    }
    #pragma unroll
    for (int off = 32; off >= 1; off >>= 1) local += __shfl_xor(local, off);
    __shared__ double sh[4];
    int lane = threadIdx.x & 63, wid = threadIdx.x >> 6;
    if (lane == 0) sh[wid] = local;
    __syncthreads();
    if (threadIdx.x == 0) {
        double tot = sh[0] + sh[1] + sh[2] + sh[3];
        out[(size_t)NTOK * DIM]     = 1.25f * sumsq[0] / (float)((size_t)NTOK * DIM);
        out[(size_t)NTOK * DIM + 1] = expf((float)(-tot));
    }
}

// ---------------------------------------------------------------------------
extern "C" void kernel_launch(void* const* d_in, const int* in_sizes, int n_in,
                              void* d_out, int out_size, void* d_ws, size_t ws_size,
                              hipStream_t stream) {
    const float* X = (const float*)d_in[0];   // [32,256,256] fp32
    const float* C = (const float*)d_in[1];   // [8192,256]   fp32
    float* out = (float*)d_out;

    char* ws = (char*)d_ws;
    size_t o = 0;
    unsigned short* Xhi = (unsigned short*)(ws + o); o += (size_t)NTOK * DIM * 2;
    unsigned short* Xlo = (unsigned short*)(ws + o); o += (size_t)NTOK * DIM * 2;
    unsigned short* Chi = (unsigned short*)(ws + o); o += (size_t)NEMB * DIM * 2;
    unsigned short* Clo = (unsigned short*)(ws + o); o += (size_t)NEMB * DIM * 2;
    float* cnorm  = (float*)(ws + o); o += (size_t)NEMB * 4;
    float* minv_p = (float*)(ws + o); o += (size_t)NPB * NTOK * 4;
    int*   mini_p = (int*)  (ws + o); o += (size_t)NPB * NTOK * 4;
    int*   idx    = (int*)  (ws + o); o += (size_t)NTOK * 4;
    int*   counts = (int*)  (ws + o); o += (size_t)NEMB * 4;
    float* sumsq  = (float*)(ws + o);

    hipMemsetAsync(counts, 0, NEMB * sizeof(int) + sizeof(float), stream);

    convert_kernel<<<dim3(NTOK * DIM / 4 / 256, 2), 256, 0, stream>>>(
        X, C, Xhi, Xlo, Chi, Clo);
    cnorm_kernel<<<NEMB / 16, 256, 0, stream>>>(C, cnorm);
    mfma_argmin_kernel<<<dim3(NTOK / 128, NEMB / 128), 256, 0, stream>>>(
        Xhi, Xlo, Chi, Clo, cnorm, minv_p, mini_p);
    reduce_idx_kernel<<<NTOK / 256, 256, 0, stream>>>(minv_p, mini_p, idx, counts);
    gather_loss_kernel<<<NTOK / 8, 256, 0, stream>>>(X, C, idx, out, sumsq);
    finalize_kernel<<<1, 256, 0, stream>>>(counts, sumsq, out);
}

// Round 4
// 258.376 us; speedup vs baseline: 74.1977x; 1.2916x over previous
//
#include <hip/hip_runtime.h>
#include <math.h>

#define NTOK 8192
#define NEMB 8192
#define DIM  256
#define NPB  64            // partial-candidate sets per token (= grid.y of GEMM)

typedef __attribute__((ext_vector_type(8))) short bf16x8;   // 8 bf16 = 4 VGPRs
typedef __attribute__((ext_vector_type(4))) float f32x4;

__device__ inline unsigned short f2bf(float f) {            // RNE fp32->bf16
    unsigned u = __builtin_bit_cast(unsigned, f);
    u = (u + 0x7fffu + ((u >> 16) & 1u)) >> 16;
    return (unsigned short)u;
}
__device__ inline float bf2f(unsigned short b) {
    unsigned u = (unsigned)b << 16;
    return __builtin_bit_cast(float, u);
}

// ---------------------------------------------------------------------------
// Kernel A: split X and C into bf16 hi/lo pairs; fused ||c||^2 (each wave of
// the C branch covers exactly one 256-elem codebook row: 64 lanes x 4 floats).
__global__ __launch_bounds__(256) void convert_kernel(
        const float* __restrict__ X, const float* __restrict__ C,
        unsigned short* __restrict__ Xhi, unsigned short* __restrict__ Xlo,
        unsigned short* __restrict__ Chi, unsigned short* __restrict__ Clo,
        float* __restrict__ cnorm) {
    const bool isC = (blockIdx.y != 0);
    const float* src = isC ? C : X;
    unsigned short* hi = isC ? Chi : Xhi;
    unsigned short* lo = isC ? Clo : Xlo;
    size_t t = (size_t)blockIdx.x * 256 + threadIdx.x;   // one float4 per thread
    float4 x = *(const float4*)&src[t * 4];
    ushort4 h, l;
    h.x = f2bf(x.x); l.x = f2bf(x.x - bf2f(h.x));
    h.y = f2bf(x.y); l.y = f2bf(x.y - bf2f(h.y));
    h.z = f2bf(x.z); l.z = f2bf(x.z - bf2f(h.z));
    h.w = f2bf(x.w); l.w = f2bf(x.w - bf2f(h.w));
    *(ushort4*)&hi[t * 4] = h;
    *(ushort4*)&lo[t * 4] = l;
    if (isC) {
        float s = x.x * x.x + x.y * x.y + x.z * x.z + x.w * x.w;
        #pragma unroll
        for (int off = 32; off >= 1; off >>= 1) s += __shfl_xor(s, off);
        if ((threadIdx.x & 63) == 0) cnorm[t >> 6] = s;
    }
}

// ---------------------------------------------------------------------------
// Kernel B: bf16-split distance GEMM (K=768 effective) + fused argmin.
// Restructured K-loop: per 64-col chunk, phase A stages {Xhi, Chi, Clo} and
// computes Xhi.Chi + Xhi.Clo (A-frags reused); phase B restages only A<-Xlo
// and computes Xlo.Chi against the resident B0. 8 staging phases, 256 KB
// staged per block (minimal). XOR-swizzled 16B granules: frag reads 2-way.
__global__ __launch_bounds__(256) void mfma_argmin_kernel(
        const unsigned short* __restrict__ Xhi, const unsigned short* __restrict__ Xlo,
        const unsigned short* __restrict__ Chi, const unsigned short* __restrict__ Clo,
        const float* __restrict__ cnorm,
        float* __restrict__ minv_p, int* __restrict__ mini_p) {
    __shared__ __align__(16) unsigned short A_lds [128 * 64];  // 16 KB
    __shared__ __align__(16) unsigned short B0_lds[128 * 64];  // 16 KB (Chi)
    __shared__ __align__(16) unsigned short B1_lds[128 * 64];  // 16 KB (Clo)
    __shared__ float cmb_v[128][2];
    __shared__ int   cmb_i[128][2];

    const int t = threadIdx.x;
    const int wid = t >> 6, lane = t & 63;
    const int m0 = blockIdx.x * 128, n0 = blockIdx.y * 128;
    const int wm = (wid >> 1) * 64, wn = (wid & 1) * 64;
    const int lrow = lane & 15;     // row-in-tile for A/B frags, col for C/D
    const int g = lane >> 4;        // quad

    f32x4 acc[4][4];                // [tm][tn]
    #pragma unroll
    for (int a = 0; a < 4; ++a)
        #pragma unroll
        for (int b = 0; b < 4; ++b) acc[a][b] = (f32x4)0.0f;

    #pragma unroll 1
    for (int c0 = 0; c0 < 4; ++c0) {
        const int colB = c0 * 64;

        // ---- phase A: stage Xhi -> A, Chi -> B0, Clo -> B1 (3072 granules)
        __syncthreads();
        #pragma unroll
        for (int c = 0; c < 12; ++c) {
            int gr  = (c & 3) * 256 + t;                 // granule 0..1023
            int row = gr >> 3, kgp = gr & 7;
            int kg  = kgp ^ (row & 7);                   // un-swizzle for global
            const unsigned short* gp;
            unsigned short* lp;
            if (c < 4)      { gp = Xhi + (size_t)(m0 + row) * DIM + colB + kg * 8;
                              lp = A_lds  + (size_t)gr * 8; }
            else if (c < 8) { gp = Chi + (size_t)(n0 + row) * DIM + colB + kg * 8;
                              lp = B0_lds + (size_t)gr * 8; }
            else            { gp = Clo + (size_t)(n0 + row) * DIM + colB + kg * 8;
                              lp = B1_lds + (size_t)gr * 8; }
            __builtin_amdgcn_global_load_lds(
                (const __attribute__((address_space(1))) void*)gp,
                (__attribute__((address_space(3))) void*)lp, 16, 0, 0);
        }
        __syncthreads();

        // ---- compute Xhi.Chi + Xhi.Clo (A-frags loaded once, used twice)
        #pragma unroll
        for (int ks = 0; ks < 2; ++ks) {
            const int kg = ks * 4 + g;
            bf16x8 af[4], bf_[4];
            #pragma unroll
            for (int tm = 0; tm < 4; ++tm) {
                int row = wm + tm * 16 + lrow;
                af[tm] = *(const bf16x8*)&A_lds[(row * 8 + (kg ^ (row & 7))) * 8];
            }
            #pragma unroll
            for (int tn = 0; tn < 4; ++tn) {
                int row = wn + tn * 16 + lrow;
                bf_[tn] = *(const bf16x8*)&B0_lds[(row * 8 + (kg ^ (row & 7))) * 8];
            }
            #pragma unroll
            for (int tm = 0; tm < 4; ++tm)
                #pragma unroll
                for (int tn = 0; tn < 4; ++tn)
                    acc[tm][tn] = __builtin_amdgcn_mfma_f32_16x16x32_bf16(
                        af[tm], bf_[tn], acc[tm][tn], 0, 0, 0);
            #pragma unroll
            for (int tn = 0; tn < 4; ++tn) {
                int row = wn + tn * 16 + lrow;
                bf_[tn] = *(const bf16x8*)&B1_lds[(row * 8 + (kg ^ (row & 7))) * 8];
            }
            #pragma unroll
            for (int tm = 0; tm < 4; ++tm)
                #pragma unroll
                for (int tn = 0; tn < 4; ++tn)
                    acc[tm][tn] = __builtin_amdgcn_mfma_f32_16x16x32_bf16(
                        af[tm], bf_[tn], acc[tm][tn], 0, 0, 0);
        }

        // ---- phase B: restage only A <- Xlo; B0 (Chi) stays resident
        __syncthreads();
        #pragma unroll
        for (int c = 0; c < 4; ++c) {
            int gr  = c * 256 + t;
            int row = gr >> 3, kgp = gr & 7;
            int kg  = kgp ^ (row & 7);
            const unsigned short* gp = Xlo + (size_t)(m0 + row) * DIM + colB + kg * 8;
            unsigned short* lp = A_lds + (size_t)gr * 8;
            __builtin_amdgcn_global_load_lds(
                (const __attribute__((address_space(1))) void*)gp,
                (__attribute__((address_space(3))) void*)lp, 16, 0, 0);
        }
        __syncthreads();

        // ---- compute Xlo.Chi
        #pragma unroll
        for (int ks = 0; ks < 2; ++ks) {
            const int kg = ks * 4 + g;
            bf16x8 af[4], bf_[4];
            #pragma unroll
            for (int tm = 0; tm < 4; ++tm) {
                int row = wm + tm * 16 + lrow;
                af[tm] = *(const bf16x8*)&A_lds[(row * 8 + (kg ^ (row & 7))) * 8];
            }
            #pragma unroll
            for (int tn = 0; tn < 4; ++tn) {
                int row = wn + tn * 16 + lrow;
                bf_[tn] = *(const bf16x8*)&B0_lds[(row * 8 + (kg ^ (row & 7))) * 8];
            }
            #pragma unroll
            for (int tm = 0; tm < 4; ++tm)
                #pragma unroll
                for (int tn = 0; tn < 4; ++tn)
                    acc[tm][tn] = __builtin_amdgcn_mfma_f32_16x16x32_bf16(
                        af[tm], bf_[tn], acc[tm][tn], 0, 0, 0);
        }
    }

    // ---- fused argmin epilogue: d = ||c||^2 - 2 x.c ----
    float cn[4];
    #pragma unroll
    for (int tn = 0; tn < 4; ++tn) cn[tn] = cnorm[n0 + wn + tn * 16 + lrow];

    #pragma unroll
    for (int tm = 0; tm < 4; ++tm) {
        #pragma unroll
        for (int reg = 0; reg < 4; ++reg) {
            float v = 1e30f; int bi = 0x7fffffff;
            #pragma unroll
            for (int tn = 0; tn < 4; ++tn) {
                float d = cn[tn] - 2.0f * acc[tm][tn][reg];
                int e = n0 + wn + tn * 16 + lrow;
                if (d < v || (d == v && e < bi)) { v = d; bi = e; }
            }
            #pragma unroll
            for (int off = 1; off < 16; off <<= 1) {   // reduce over the 16 cols
                float ov = __shfl_xor(v, off);
                int   oi = __shfl_xor(bi, off);
                if (ov < v || (ov == v && oi < bi)) { v = ov; bi = oi; }
            }
            if (lrow == 0) {
                int r = wm + tm * 16 + g * 4 + reg;    // C/D: row = quad*4 + reg
                cmb_v[r][wid & 1] = v; cmb_i[r][wid & 1] = bi;
            }
        }
    }
    __syncthreads();
    if (t < 128) {
        float v0 = cmb_v[t][0], v1 = cmb_v[t][1];
        int   i0 = cmb_i[t][0], i1 = cmb_i[t][1];
        bool tk = (v1 < v0) || (v1 == v0 && i1 < i0);
        minv_p[(size_t)blockIdx.y * NTOK + m0 + t] = tk ? v1 : v0;
        mini_p[(size_t)blockIdx.y * NTOK + m0 + t] = tk ? i1 : i0;
    }
}

// ---------------------------------------------------------------------------
// Kernel C: fold the NPB candidates per token, gather codebook rows -> out,
// per-block partial sum of (q-x)^2 (no global atomics, no memset needed).
// 256 blocks x 32 tokens.
__global__ __launch_bounds__(256) void reduce_gather_kernel(
        const float* __restrict__ X, const float* __restrict__ C,
        const float* __restrict__ minv_p, const int* __restrict__ mini_p,
        int* __restrict__ idx, float* __restrict__ out,
        float* __restrict__ psum) {
    __shared__ int   idx_lds[32];
    __shared__ float wsum[4];
    const int m0 = blockIdx.x * 32;
    const int t = threadIdx.x;
    if (t < 32) {
        int token = m0 + t;
        float bv = 1e30f; int bi = 0x7fffffff;
        #pragma unroll 1
        for (int p = 0; p < NPB; ++p) {
            float v = minv_p[(size_t)p * NTOK + token];
            int   i = mini_p[(size_t)p * NTOK + token];
            if (v < bv || (v == bv && i < bi)) { bv = v; bi = i; }
        }
        idx[token] = bi;
        idx_lds[t] = bi;
    }
    __syncthreads();
    const int wid = t >> 6, lane = t & 63;
    float local = 0.0f;
    #pragma unroll
    for (int r = 0; r < 8; ++r) {
        int token = m0 + wid * 8 + r;
        int e = idx_lds[wid * 8 + r];
        float4 q = *(const float4*)&C[(size_t)e * DIM + lane * 4];
        float4 x = *(const float4*)&X[(size_t)token * DIM + lane * 4];
        *(float4*)&out[(size_t)token * DIM + lane * 4] = q;
        float d0 = q.x - x.x, d1 = q.y - x.y, d2 = q.z - x.z, d3 = q.w - x.w;
        local += d0 * d0 + d1 * d1 + d2 * d2 + d3 * d3;
    }
    #pragma unroll
    for (int off = 32; off >= 1; off >>= 1) local += __shfl_xor(local, off);
    if (lane == 0) wsum[wid] = local;
    __syncthreads();
    if (t == 0) psum[blockIdx.x] = wsum[0] + wsum[1] + wsum[2] + wsum[3];
}

// ---------------------------------------------------------------------------
// Kernel D: histogram in LDS from idx[], entropy, loss. Single block.
__global__ __launch_bounds__(256) void finalize_kernel(
        const int* __restrict__ idx, const float* __restrict__ psum,
        float* __restrict__ out) {
    __shared__ int hist[NEMB];   // 32 KB
    const int t = threadIdx.x;
    for (int i = t; i < NEMB; i += 256) hist[i] = 0;
    __syncthreads();
    for (int i = t; i < NTOK; i += 256) atomicAdd(&hist[idx[i]], 1);
    __syncthreads();
    double local = 0.0;
    for (int e = t; e < NEMB; e += 256) {
        float p = (float)hist[e] * (1.0f / (float)NTOK);
        local += (double)(p * logf(p + 1e-10f));
    }
    float ls = psum[t];          // 256 threads, 256 partial sums
    #pragma unroll
    for (int off = 32; off >= 1; off >>= 1) {
        local += __shfl_xor(local, off);
        ls    += __shfl_xor(ls, off);
    }
    __shared__ double she[4];
    __shared__ float  shs[4];
    int lane = t & 63, wid = t >> 6;
    if (lane == 0) { she[wid] = local; shs[wid] = ls; }
    __syncthreads();
    if (t == 0) {
        double ent = she[0] + she[1] + she[2] + she[3];
        float  ssq = shs[0] + shs[1] + shs[2] + shs[3];
        out[(size_t)NTOK * DIM]     = 1.25f * ssq / (float)((size_t)NTOK * DIM);
        out[(size_t)NTOK * DIM + 1] = expf((float)(-ent));
    }
}

// ---------------------------------------------------------------------------
extern "C" void kernel_launch(void* const* d_in, const int* in_sizes, int n_in,
                              void* d_out, int out_size, void* d_ws, size_t ws_size,
                              hipStream_t stream) {
    const float* X = (const float*)d_in[0];   // [32,256,256] fp32
    const float* C = (const float*)d_in[1];   // [8192,256]   fp32
    float* out = (float*)d_out;

    char* ws = (char*)d_ws;
    size_t o = 0;
    unsigned short* Xhi = (unsigned short*)(ws + o); o += (size_t)NTOK * DIM * 2;
    unsigned short* Xlo = (unsigned short*)(ws + o); o += (size_t)NTOK * DIM * 2;
    unsigned short* Chi = (unsigned short*)(ws + o); o += (size_t)NEMB * DIM * 2;
    unsigned short* Clo = (unsigned short*)(ws + o); o += (size_t)NEMB * DIM * 2;
    float* cnorm  = (float*)(ws + o); o += (size_t)NEMB * 4;
    float* minv_p = (float*)(ws + o); o += (size_t)NPB * NTOK * 4;
    int*   mini_p = (int*)  (ws + o); o += (size_t)NPB * NTOK * 4;
    int*   idx    = (int*)  (ws + o); o += (size_t)NTOK * 4;
    float* psum   = (float*)(ws + o);

    convert_kernel<<<dim3(NTOK * DIM / 4 / 256, 2), 256, 0, stream>>>(
        X, C, Xhi, Xlo, Chi, Clo, cnorm);
    mfma_argmin_kernel<<<dim3(NTOK / 128, NEMB / 128), 256, 0, stream>>>(
        Xhi, Xlo, Chi, Clo, cnorm, minv_p, mini_p);
    reduce_gather_kernel<<<256, 256, 0, stream>>>(
        X, C, minv_p, mini_p, idx, out, psum);
    finalize_kernel<<<1, 256, 0, stream>>>(idx, psum, out);
}

// Round 5
// 250.790 us; speedup vs baseline: 76.4420x; 1.0302x over previous
//
#include <hip/hip_runtime.h>
#include <math.h>

#define NTOK 8192
#define NEMB 8192
#define DIM  256
#define NPB  64            // partial-candidate sets per token (= grid.y of GEMM)

typedef __attribute__((ext_vector_type(8))) short bf16x8;   // 8 bf16 = 4 VGPRs
typedef __attribute__((ext_vector_type(4))) float f32x4;

__device__ inline unsigned short f2bf(float f) {            // RNE fp32->bf16
    unsigned u = __builtin_bit_cast(unsigned, f);
    u = (u + 0x7fffu + ((u >> 16) & 1u)) >> 16;
    return (unsigned short)u;
}
__device__ inline float bf2f(unsigned short b) {
    unsigned u = (unsigned)b << 16;
    return __builtin_bit_cast(float, u);
}

// ---------------------------------------------------------------------------
// Kernel A: split X and C into bf16 hi/lo pairs; fused ||c||^2 (each wave of
// the C branch covers exactly one 256-elem codebook row). Blocks x<8 of the
// C branch also zero the histogram buffer (used later by reduce_gather).
__global__ __launch_bounds__(256) void convert_kernel(
        const float* __restrict__ X, const float* __restrict__ C,
        unsigned short* __restrict__ Xhi, unsigned short* __restrict__ Xlo,
        unsigned short* __restrict__ Chi, unsigned short* __restrict__ Clo,
        float* __restrict__ cnorm, int* __restrict__ counts) {
    const bool isC = (blockIdx.y != 0);
    if (isC && blockIdx.x < 8) {
        ((int4*)counts)[blockIdx.x * 256 + threadIdx.x] = make_int4(0, 0, 0, 0);
    }
    const float* src = isC ? C : X;
    unsigned short* hi = isC ? Chi : Xhi;
    unsigned short* lo = isC ? Clo : Xlo;
    size_t t = (size_t)blockIdx.x * 256 + threadIdx.x;   // one float4 per thread
    float4 x = *(const float4*)&src[t * 4];
    ushort4 h, l;
    h.x = f2bf(x.x); l.x = f2bf(x.x - bf2f(h.x));
    h.y = f2bf(x.y); l.y = f2bf(x.y - bf2f(h.y));
    h.z = f2bf(x.z); l.z = f2bf(x.z - bf2f(h.z));
    h.w = f2bf(x.w); l.w = f2bf(x.w - bf2f(h.w));
    *(ushort4*)&hi[t * 4] = h;
    *(ushort4*)&lo[t * 4] = l;
    if (isC) {
        float s = x.x * x.x + x.y * x.y + x.z * x.z + x.w * x.w;
        #pragma unroll
        for (int off = 32; off >= 1; off >>= 1) s += __shfl_xor(s, off);
        if ((threadIdx.x & 63) == 0) cnorm[t >> 6] = s;
    }
}

// ---------------------------------------------------------------------------
// Staging: 1024 16B granules (128 rows x 64 cols bf16) by 256 threads.
// XOR swizzle on granule column by (row&7) so frag ds_read_b128 is conflict-
// free while global_load_lds stays lane-contiguous.
__device__ __forceinline__ void stage_tile(const unsigned short* __restrict__ gbase,
                                           unsigned short* lds, int t) {
    #pragma unroll
    for (int c = 0; c < 4; ++c) {
        int gr  = c * 256 + t;
        int row = gr >> 3, kgp = gr & 7;
        int kg  = kgp ^ (row & 7);                   // un-swizzle for global
        const unsigned short* gp = gbase + (size_t)row * DIM + kg * 8;
        unsigned short* lp = lds + (size_t)gr * 8;
        __builtin_amdgcn_global_load_lds(
            (const __attribute__((address_space(1))) void*)gp,
            (__attribute__((address_space(3))) void*)lp, 16, 0, 0);
    }
}

__device__ __forceinline__ void compute_tile(const unsigned short* A_lds,
                                             const unsigned short* B_lds,
                                             f32x4 (&acc)[4][4],
                                             int wm, int wn, int lrow, int g) {
    #pragma unroll
    for (int ks = 0; ks < 2; ++ks) {
        const int kg = ks * 4 + g;
        bf16x8 af[4], bf_[4];
        #pragma unroll
        for (int tm = 0; tm < 4; ++tm) {
            int row = wm + tm * 16 + lrow;
            af[tm] = *(const bf16x8*)&A_lds[(row * 8 + (kg ^ (row & 7))) * 8];
        }
        #pragma unroll
        for (int tn = 0; tn < 4; ++tn) {
            int row = wn + tn * 16 + lrow;
            bf_[tn] = *(const bf16x8*)&B_lds[(row * 8 + (kg ^ (row & 7))) * 8];
        }
        #pragma unroll
        for (int tm = 0; tm < 4; ++tm)
            #pragma unroll
            for (int tn = 0; tn < 4; ++tn)
                acc[tm][tn] = __builtin_amdgcn_mfma_f32_16x16x32_bf16(
                    af[tm], bf_[tn], acc[tm][tn], 0, 0, 0);
    }
}

// ---------------------------------------------------------------------------
// Kernel B: bf16-split distance GEMM (K=768 effective) + fused argmin.
// 2 LDS buffers (32 KB total -> 4 blocks/CU). Per 64-col chunk:
//   stage{A=Xhi,B=Chi} -> hi.hi ; restage{A=Xlo} -> lo.hi (B resident) ;
//   restage{A=Xhi,B=Clo} -> hi.lo.
__global__ __launch_bounds__(256) void mfma_argmin_kernel(
        const unsigned short* __restrict__ Xhi, const unsigned short* __restrict__ Xlo,
        const unsigned short* __restrict__ Chi, const unsigned short* __restrict__ Clo,
        const float* __restrict__ cnorm,
        float* __restrict__ minv_p, int* __restrict__ mini_p) {
    __shared__ __align__(16) unsigned short A_lds[128 * 64];  // 16 KB
    __shared__ __align__(16) unsigned short B_lds[128 * 64];  // 16 KB

    const int t = threadIdx.x;
    const int wid = t >> 6, lane = t & 63;
    const int m0 = blockIdx.x * 128, n0 = blockIdx.y * 128;
    const int wm = (wid >> 1) * 64, wn = (wid & 1) * 64;
    const int lrow = lane & 15;     // row-in-tile for A/B frags, col for C/D
    const int g = lane >> 4;        // quad

    f32x4 acc[4][4];                // [tm][tn]
    #pragma unroll
    for (int a = 0; a < 4; ++a)
        #pragma unroll
        for (int b = 0; b < 4; ++b) acc[a][b] = (f32x4)0.0f;

    #pragma unroll 1
    for (int c0 = 0; c0 < 4; ++c0) {
        const size_t offA = (size_t)m0 * DIM + c0 * 64;
        const size_t offB = (size_t)n0 * DIM + c0 * 64;

        __syncthreads();                       // buffers free from prev compute
        stage_tile(Xhi + offA, A_lds, t);
        stage_tile(Chi + offB, B_lds, t);
        __syncthreads();
        compute_tile(A_lds, B_lds, acc, wm, wn, lrow, g);   // hi.hi

        __syncthreads();
        stage_tile(Xlo + offA, A_lds, t);
        __syncthreads();
        compute_tile(A_lds, B_lds, acc, wm, wn, lrow, g);   // lo.hi

        __syncthreads();
        stage_tile(Xhi + offA, A_lds, t);
        stage_tile(Clo + offB, B_lds, t);
        __syncthreads();
        compute_tile(A_lds, B_lds, acc, wm, wn, lrow, g);   // hi.lo
    }

    // ---- fused argmin epilogue: d = ||c||^2 - 2 x.c ----
    float cn[4];
    #pragma unroll
    for (int tn = 0; tn < 4; ++tn) cn[tn] = cnorm[n0 + wn + tn * 16 + lrow];

    __syncthreads();                            // A_lds reuse as cmb scratch
    float* cmb_v = (float*)A_lds;               // [128][2]
    int*   cmb_i = (int*)(A_lds + 1024);        // [128][2]

    #pragma unroll
    for (int tm = 0; tm < 4; ++tm) {
        #pragma unroll
        for (int reg = 0; reg < 4; ++reg) {
            float v = 1e30f; int bi = 0x7fffffff;
            #pragma unroll
            for (int tn = 0; tn < 4; ++tn) {
                float d = cn[tn] - 2.0f * acc[tm][tn][reg];
                int e = n0 + wn + tn * 16 + lrow;
                if (d < v || (d == v && e < bi)) { v = d; bi = e; }
            }
            #pragma unroll
            for (int off = 1; off < 16; off <<= 1) {   // reduce over the 16 cols
                float ov = __shfl_xor(v, off);
                int   oi = __shfl_xor(bi, off);
                if (ov < v || (ov == v && oi < bi)) { v = ov; bi = oi; }
            }
            if (lrow == 0) {
                int r = wm + tm * 16 + g * 4 + reg;    // C/D: row = quad*4 + reg
                cmb_v[r * 2 + (wid & 1)] = v; cmb_i[r * 2 + (wid & 1)] = bi;
            }
        }
    }
    __syncthreads();
    if (t < 128) {
        float v0 = cmb_v[t * 2], v1 = cmb_v[t * 2 + 1];
        int   i0 = cmb_i[t * 2], i1 = cmb_i[t * 2 + 1];
        bool tk = (v1 < v0) || (v1 == v0 && i1 < i0);
        minv_p[(size_t)blockIdx.y * NTOK + m0 + t] = tk ? v1 : v0;
        mini_p[(size_t)blockIdx.y * NTOK + m0 + t] = tk ? i1 : i0;
    }
}

// ---------------------------------------------------------------------------
// Kernel C: fold the NPB candidates per token (8 threads/token), histogram
// via device atomics, gather codebook rows -> out, per-block loss partial.
// 256 blocks x 32 tokens.
__global__ __launch_bounds__(256) void reduce_gather_kernel(
        const float* __restrict__ X, const float* __restrict__ C,
        const float* __restrict__ minv_p, const int* __restrict__ mini_p,
        int* __restrict__ counts, float* __restrict__ out,
        float* __restrict__ psum) {
    __shared__ int   idx_lds[32];
    __shared__ float wsum[4];
    const int m0 = blockIdx.x * 32;
    const int t = threadIdx.x;
    {
        const int tl = t >> 3;          // token-local 0..31
        const int pc = t & 7;           // partial chunk 0..7
        int token = m0 + tl;
        float bv = 1e30f; int bi = 0x7fffffff;
        #pragma unroll
        for (int i = 0; i < 8; ++i) {
            int p = pc * 8 + i;
            float v  = minv_p[(size_t)p * NTOK + token];
            int   ii = mini_p[(size_t)p * NTOK + token];
            if (v < bv || (v == bv && ii < bi)) { bv = v; bi = ii; }
        }
        #pragma unroll
        for (int off = 1; off < 8; off <<= 1) {
            float ov = __shfl_xor(bv, off);
            int   oi = __shfl_xor(bi, off);
            if (ov < bv || (ov == bv && oi < bi)) { bv = ov; bi = oi; }
        }
        if (pc == 0) { idx_lds[tl] = bi; atomicAdd(&counts[bi], 1); }
    }
    __syncthreads();
    const int wid = t >> 6, lane = t & 63;
    float local = 0.0f;
    #pragma unroll
    for (int r = 0; r < 8; ++r) {
        int token = m0 + wid * 8 + r;
        int e = idx_lds[wid * 8 + r];
        float4 q = *(const float4*)&C[(size_t)e * DIM + lane * 4];
        float4 x = *(const float4*)&X[(size_t)token * DIM + lane * 4];
        *(float4*)&out[(size_t)token * DIM + lane * 4] = q;
        float d0 = q.x - x.x, d1 = q.y - x.y, d2 = q.z - x.z, d3 = q.w - x.w;
        local += d0 * d0 + d1 * d1 + d2 * d2 + d3 * d3;
    }
    #pragma unroll
    for (int off = 32; off >= 1; off >>= 1) local += __shfl_xor(local, off);
    if (lane == 0) wsum[wid] = local;
    __syncthreads();
    if (t == 0) psum[blockIdx.x] = wsum[0] + wsum[1] + wsum[2] + wsum[3];
}

// ---------------------------------------------------------------------------
// Kernel D: entropy over the 8192-bin histogram + loss. Single small block.
__global__ __launch_bounds__(256) void finalize_kernel(
        const int* __restrict__ counts, const float* __restrict__ psum,
        float* __restrict__ out) {
    const int t = threadIdx.x;
    double local = 0.0;
    #pragma unroll 1
    for (int e = t; e < NEMB; e += 256) {
        float p = (float)counts[e] * (1.0f / (float)NTOK);
        local += (double)(p * logf(p + 1e-10f));
    }
    float ls = psum[t];          // 256 threads, 256 partial sums
    #pragma unroll
    for (int off = 32; off >= 1; off >>= 1) {
        local += __shfl_xor(local, off);
        ls    += __shfl_xor(ls, off);
    }
    __shared__ double she[4];
    __shared__ float  shs[4];
    int lane = t & 63, wid = t >> 6;
    if (lane == 0) { she[wid] = local; shs[wid] = ls; }
    __syncthreads();
    if (t == 0) {
        double ent = she[0] + she[1] + she[2] + she[3];
        float  ssq = shs[0] + shs[1] + shs[2] + shs[3];
        out[(size_t)NTOK * DIM]     = 1.25f * ssq / (float)((size_t)NTOK * DIM);
        out[(size_t)NTOK * DIM + 1] = expf((float)(-ent));
    }
}

// ---------------------------------------------------------------------------
extern "C" void kernel_launch(void* const* d_in, const int* in_sizes, int n_in,
                              void* d_out, int out_size, void* d_ws, size_t ws_size,
                              hipStream_t stream) {
    const float* X = (const float*)d_in[0];   // [32,256,256] fp32
    const float* C = (const float*)d_in[1];   // [8192,256]   fp32
    float* out = (float*)d_out;

    char* ws = (char*)d_ws;
    size_t o = 0;
    unsigned short* Xhi = (unsigned short*)(ws + o); o += (size_t)NTOK * DIM * 2;
    unsigned short* Xlo = (unsigned short*)(ws + o); o += (size_t)NTOK * DIM * 2;
    unsigned short* Chi = (unsigned short*)(ws + o); o += (size_t)NEMB * DIM * 2;
    unsigned short* Clo = (unsigned short*)(ws + o); o += (size_t)NEMB * DIM * 2;
    float* cnorm  = (float*)(ws + o); o += (size_t)NEMB * 4;
    float* minv_p = (float*)(ws + o); o += (size_t)NPB * NTOK * 4;
    int*   mini_p = (int*)  (ws + o); o += (size_t)NPB * NTOK * 4;
    int*   counts = (int*)  (ws + o); o += (size_t)NEMB * 4;
    float* psum   = (float*)(ws + o);

    convert_kernel<<<dim3(NTOK * DIM / 4 / 256, 2), 256, 0, stream>>>(
        X, C, Xhi, Xlo, Chi, Clo, cnorm, counts);
    mfma_argmin_kernel<<<dim3(NTOK / 128, NEMB / 128), 256, 0, stream>>>(
        Xhi, Xlo, Chi, Clo, cnorm, minv_p, mini_p);
    reduce_gather_kernel<<<256, 256, 0, stream>>>(
        X, C, minv_p, mini_p, counts, out, psum);
    finalize_kernel<<<1, 256, 0, stream>>>(counts, psum, out);
}

// Round 6
// 203.710 us; speedup vs baseline: 94.1087x; 1.2311x over previous
//
#include <hip/hip_runtime.h>
#include <math.h>

#define NTOK 8192
#define NEMB 8192
#define DIM  256
#define NPB  64            // partial-candidate sets per token (= grid.y of GEMM)

typedef _Float16 f16x8 __attribute__((ext_vector_type(8)));   // 4 VGPRs
typedef _Float16 f16x4 __attribute__((ext_vector_type(4)));
typedef float    f32x4 __attribute__((ext_vector_type(4)));

// ---------------------------------------------------------------------------
// Kernel A: cast X and C to fp16 (RNE); fused exact fp32 ||c||^2 (each wave of
// the C branch covers exactly one 256-elem codebook row). Blocks x<8 of the
// C branch also zero the histogram buffer.
__global__ __launch_bounds__(256) void convert_kernel(
        const float* __restrict__ X, const float* __restrict__ C,
        _Float16* __restrict__ Xh, _Float16* __restrict__ Ch,
        float* __restrict__ cnorm, int* __restrict__ counts) {
    const bool isC = (blockIdx.y != 0);
    if (isC && blockIdx.x < 8) {
        ((int4*)counts)[blockIdx.x * 256 + threadIdx.x] = make_int4(0, 0, 0, 0);
    }
    const float* src = isC ? C : X;
    _Float16* dst = isC ? Ch : Xh;
    size_t t = (size_t)blockIdx.x * 256 + threadIdx.x;   // one float4 per thread
    float4 x = *(const float4*)&src[t * 4];
    f16x4 h;
    h[0] = (_Float16)x.x; h[1] = (_Float16)x.y;
    h[2] = (_Float16)x.z; h[3] = (_Float16)x.w;
    *(f16x4*)&dst[t * 4] = h;
    if (isC) {
        float s = x.x * x.x + x.y * x.y + x.z * x.z + x.w * x.w;
        #pragma unroll
        for (int off = 32; off >= 1; off >>= 1) s += __shfl_xor(s, off);
        if ((threadIdx.x & 63) == 0) cnorm[t >> 6] = s;
    }
}

// ---------------------------------------------------------------------------
// Kernel B: fp16 distance GEMM (K=256, fp32 accum) + fused argmin.
// Grid (64,64), 256 threads = 4 waves 2x2, wave tile 64x64 as 4x4 MFMA
// 16x16x32_f16. K in 4 chunks of 64: per chunk stage A(16KB)+B(16KB) via
// global_load_lds width-16, compute 32 MFMAs/wave. 16B granules XOR-swizzled
// by (row&7): frag ds_read_b128 2-way (free), staging lane-contiguous.
__global__ __launch_bounds__(256) void mfma_argmin_kernel(
        const _Float16* __restrict__ Xh, const _Float16* __restrict__ Ch,
        const float* __restrict__ cnorm,
        float* __restrict__ minv_p, int* __restrict__ mini_p) {
    __shared__ __align__(16) _Float16 A_lds[128 * 64];  // 16 KB
    __shared__ __align__(16) _Float16 B_lds[128 * 64];  // 16 KB

    const int t = threadIdx.x;
    const int wid = t >> 6, lane = t & 63;
    const int m0 = blockIdx.x * 128, n0 = blockIdx.y * 128;
    const int wm = (wid >> 1) * 64, wn = (wid & 1) * 64;
    const int lrow = lane & 15;     // row-in-tile for A/B frags, col for C/D
    const int g = lane >> 4;        // quad

    f32x4 acc[4][4];                // [tm][tn]
    #pragma unroll
    for (int a = 0; a < 4; ++a)
        #pragma unroll
        for (int b = 0; b < 4; ++b) acc[a][b] = (f32x4)0.0f;

    #pragma unroll 1
    for (int c0 = 0; c0 < 4; ++c0) {
        const _Float16* Ag = Xh + (size_t)m0 * DIM + c0 * 64;
        const _Float16* Bg = Ch + (size_t)n0 * DIM + c0 * 64;

        __syncthreads();                       // buffers free from prev compute
        #pragma unroll
        for (int c = 0; c < 4; ++c) {
            int gr  = c * 256 + t;                   // granule 0..1023
            int row = gr >> 3, kgp = gr & 7;
            int kg  = kgp ^ (row & 7);               // un-swizzle for global
            __builtin_amdgcn_global_load_lds(
                (const __attribute__((address_space(1))) void*)(Ag + (size_t)row * DIM + kg * 8),
                (__attribute__((address_space(3))) void*)(A_lds + (size_t)gr * 8), 16, 0, 0);
            __builtin_amdgcn_global_load_lds(
                (const __attribute__((address_space(1))) void*)(Bg + (size_t)row * DIM + kg * 8),
                (__attribute__((address_space(3))) void*)(B_lds + (size_t)gr * 8), 16, 0, 0);
        }
        __syncthreads();

        #pragma unroll
        for (int ks = 0; ks < 2; ++ks) {
            const int kg = ks * 4 + g;
            f16x8 af[4], bf_[4];
            #pragma unroll
            for (int tm = 0; tm < 4; ++tm) {
                int row = wm + tm * 16 + lrow;
                af[tm] = *(const f16x8*)&A_lds[(row * 8 + (kg ^ (row & 7))) * 8];
            }
            #pragma unroll
            for (int tn = 0; tn < 4; ++tn) {
                int row = wn + tn * 16 + lrow;
                bf_[tn] = *(const f16x8*)&B_lds[(row * 8 + (kg ^ (row & 7))) * 8];
            }
            #pragma unroll
            for (int tm = 0; tm < 4; ++tm)
                #pragma unroll
                for (int tn = 0; tn < 4; ++tn)
                    acc[tm][tn] = __builtin_amdgcn_mfma_f32_16x16x32_f16(
                        af[tm], bf_[tn], acc[tm][tn], 0, 0, 0);
        }
    }

    // ---- fused argmin epilogue: d = ||c||^2 - 2 x.c ----
    float cn[4];
    #pragma unroll
    for (int tn = 0; tn < 4; ++tn) cn[tn] = cnorm[n0 + wn + tn * 16 + lrow];

    __syncthreads();                            // A_lds reuse as cmb scratch
    float* cmb_v = (float*)A_lds;               // [128][2]
    int*   cmb_i = (int*)(A_lds + 2048);        // [128][2]

    #pragma unroll
    for (int tm = 0; tm < 4; ++tm) {
        #pragma unroll
        for (int reg = 0; reg < 4; ++reg) {
            float v = 1e30f; int bi = 0x7fffffff;
            #pragma unroll
            for (int tn = 0; tn < 4; ++tn) {
                float d = cn[tn] - 2.0f * acc[tm][tn][reg];
                int e = n0 + wn + tn * 16 + lrow;
                if (d < v || (d == v && e < bi)) { v = d; bi = e; }
            }
            #pragma unroll
            for (int off = 1; off < 16; off <<= 1) {   // reduce over the 16 cols
                float ov = __shfl_xor(v, off);
                int   oi = __shfl_xor(bi, off);
                if (ov < v || (ov == v && oi < bi)) { v = ov; bi = oi; }
            }
            if (lrow == 0) {
                int r = wm + tm * 16 + g * 4 + reg;    // C/D: row = quad*4 + reg
                cmb_v[r * 2 + (wid & 1)] = v; cmb_i[r * 2 + (wid & 1)] = bi;
            }
        }
    }
    __syncthreads();
    if (t < 128) {
        float v0 = cmb_v[t * 2], v1 = cmb_v[t * 2 + 1];
        int   i0 = cmb_i[t * 2], i1 = cmb_i[t * 2 + 1];
        bool tk = (v1 < v0) || (v1 == v0 && i1 < i0);
        minv_p[(size_t)blockIdx.y * NTOK + m0 + t] = tk ? v1 : v0;
        mini_p[(size_t)blockIdx.y * NTOK + m0 + t] = tk ? i1 : i0;
    }
}

// ---------------------------------------------------------------------------
// Kernel C: fold the NPB candidates per token (8 threads/token), histogram
// via device atomics, gather codebook rows -> out, per-block loss partial.
__global__ __launch_bounds__(256) void reduce_gather_kernel(
        const float* __restrict__ X, const float* __restrict__ C,
        const float* __restrict__ minv_p, const int* __restrict__ mini_p,
        int* __restrict__ counts, float* __restrict__ out,
        float* __restrict__ psum) {
    __shared__ int   idx_lds[32];
    __shared__ float wsum[4];
    const int m0 = blockIdx.x * 32;
    const int t = threadIdx.x;
    {
        const int tl = t >> 3;          // token-local 0..31
        const int pc = t & 7;           // partial chunk 0..7
        int token = m0 + tl;
        float bv = 1e30f; int bi = 0x7fffffff;
        #pragma unroll
        for (int i = 0; i < 8; ++i) {
            int p = pc * 8 + i;
            float v  = minv_p[(size_t)p * NTOK + token];
            int   ii = mini_p[(size_t)p * NTOK + token];
            if (v < bv || (v == bv && ii < bi)) { bv = v; bi = ii; }
        }
        #pragma unroll
        for (int off = 1; off < 8; off <<= 1) {
            float ov = __shfl_xor(bv, off);
            int   oi = __shfl_xor(bi, off);
            if (ov < bv || (ov == bv && oi < bi)) { bv = ov; bi = oi; }
        }
        if (pc == 0) { idx_lds[tl] = bi; atomicAdd(&counts[bi], 1); }
    }
    __syncthreads();
    const int wid = t >> 6, lane = t & 63;
    float local = 0.0f;
    #pragma unroll
    for (int r = 0; r < 8; ++r) {
        int token = m0 + wid * 8 + r;
        int e = idx_lds[wid * 8 + r];
        float4 q = *(const float4*)&C[(size_t)e * DIM + lane * 4];
        float4 x = *(const float4*)&X[(size_t)token * DIM + lane * 4];
        *(float4*)&out[(size_t)token * DIM + lane * 4] = q;
        float d0 = q.x - x.x, d1 = q.y - x.y, d2 = q.z - x.z, d3 = q.w - x.w;
        local += d0 * d0 + d1 * d1 + d2 * d2 + d3 * d3;
    }
    #pragma unroll
    for (int off = 32; off >= 1; off >>= 1) local += __shfl_xor(local, off);
    if (lane == 0) wsum[wid] = local;
    __syncthreads();
    if (t == 0) psum[blockIdx.x] = wsum[0] + wsum[1] + wsum[2] + wsum[3];
}

// ---------------------------------------------------------------------------
// Kernel D: entropy over the 8192-bin histogram + loss. Single small block.
__global__ __launch_bounds__(256) void finalize_kernel(
        const int* __restrict__ counts, const float* __restrict__ psum,
        float* __restrict__ out) {
    const int t = threadIdx.x;
    double local = 0.0;
    #pragma unroll 1
    for (int e = t; e < NEMB; e += 256) {
        float p = (float)counts[e] * (1.0f / (float)NTOK);
        local += (double)(p * logf(p + 1e-10f));
    }
    float ls = psum[t];          // 256 threads, 256 partial sums
    #pragma unroll
    for (int off = 32; off >= 1; off >>= 1) {
        local += __shfl_xor(local, off);
        ls    += __shfl_xor(ls, off);
    }
    __shared__ double she[4];
    __shared__ float  shs[4];
    int lane = t & 63, wid = t >> 6;
    if (lane == 0) { she[wid] = local; shs[wid] = ls; }
    __syncthreads();
    if (t == 0) {
        double ent = she[0] + she[1] + she[2] + she[3];
        float  ssq = shs[0] + shs[1] + shs[2] + shs[3];
        out[(size_t)NTOK * DIM]     = 1.25f * ssq / (float)((size_t)NTOK * DIM);
        out[(size_t)NTOK * DIM + 1] = expf((float)(-ent));
    }
}

// ---------------------------------------------------------------------------
extern "C" void kernel_launch(void* const* d_in, const int* in_sizes, int n_in,
                              void* d_out, int out_size, void* d_ws, size_t ws_size,
                              hipStream_t stream) {
    const float* X = (const float*)d_in[0];   // [32,256,256] fp32
    const float* C = (const float*)d_in[1];   // [8192,256]   fp32
    float* out = (float*)d_out;

    char* ws = (char*)d_ws;
    size_t o = 0;
    _Float16* Xh = (_Float16*)(ws + o); o += (size_t)NTOK * DIM * 2;
    _Float16* Ch = (_Float16*)(ws + o); o += (size_t)NEMB * DIM * 2;
    float* cnorm  = (float*)(ws + o); o += (size_t)NEMB * 4;
    float* minv_p = (float*)(ws + o); o += (size_t)NPB * NTOK * 4;
    int*   mini_p = (int*)  (ws + o); o += (size_t)NPB * NTOK * 4;
    int*   counts = (int*)  (ws + o); o += (size_t)NEMB * 4;
    float* psum   = (float*)(ws + o);

    convert_kernel<<<dim3(NTOK * DIM / 4 / 256, 2), 256, 0, stream>>>(
        X, C, Xh, Ch, cnorm, counts);
    mfma_argmin_kernel<<<dim3(NTOK / 128, NEMB / 128), 256, 0, stream>>>(
        Xh, Ch, cnorm, minv_p, mini_p);
    reduce_gather_kernel<<<256, 256, 0, stream>>>(
        X, C, minv_p, mini_p, counts, out, psum);
    finalize_kernel<<<1, 256, 0, stream>>>(counts, psum, out);
}

// Round 7
// 135.684 us; speedup vs baseline: 141.2903x; 1.5014x over previous
//
#include <hip/hip_runtime.h>
#include <math.h>

#define NTOK 8192
#define NEMB 8192
#define DIM  256
#define NPB  64            // partial-candidate sets per token (= grid.y of GEMM)

typedef _Float16 f16x8 __attribute__((ext_vector_type(8)));   // 4 VGPRs
typedef _Float16 f16x4 __attribute__((ext_vector_type(4)));
typedef float    f32x4 __attribute__((ext_vector_type(4)));

// ---------------------------------------------------------------------------
// Kernel A: cast X and C to fp16 (RNE); fused exact fp32 ||c||^2 (each wave of
// the C branch covers exactly one 256-elem codebook row). Blocks x<8 of the
// C branch also zero the histogram buffer.
__global__ __launch_bounds__(256) void convert_kernel(
        const float* __restrict__ X, const float* __restrict__ C,
        _Float16* __restrict__ Xh, _Float16* __restrict__ Ch,
        float* __restrict__ cnorm, int* __restrict__ counts) {
    const bool isC = (blockIdx.y != 0);
    if (isC && blockIdx.x < 8) {
        ((int4*)counts)[blockIdx.x * 256 + threadIdx.x] = make_int4(0, 0, 0, 0);
    }
    const float* src = isC ? C : X;
    _Float16* dst = isC ? Ch : Xh;
    size_t t = (size_t)blockIdx.x * 256 + threadIdx.x;   // one float4 per thread
    float4 x = *(const float4*)&src[t * 4];
    f16x4 h;
    h[0] = (_Float16)x.x; h[1] = (_Float16)x.y;
    h[2] = (_Float16)x.z; h[3] = (_Float16)x.w;
    *(f16x4*)&dst[t * 4] = h;
    if (isC) {
        float s = x.x * x.x + x.y * x.y + x.z * x.z + x.w * x.w;
        #pragma unroll
        for (int off = 32; off >= 1; off >>= 1) s += __shfl_xor(s, off);
        if ((threadIdx.x & 63) == 0) cnorm[t >> 6] = s;
    }
}

// ---------------------------------------------------------------------------
// Stage one 128x64 fp16 tile pair (A=codes, B=tokens) into LDS buffers via
// global_load_lds width-16. 16B granules XOR-swizzled by (row&7): frag
// ds_read_b128 <=2-way (free), staging lane-contiguous.
__device__ __forceinline__ void stage_pair(
        const _Float16* __restrict__ Ag, const _Float16* __restrict__ Bg,
        _Float16* Abase, _Float16* Bbase, int t) {
    #pragma unroll
    for (int c = 0; c < 4; ++c) {
        int gr  = c * 256 + t;                   // granule 0..1023
        int row = gr >> 3;
        int kg  = (gr & 7) ^ (row & 7);          // un-swizzle for global
        __builtin_amdgcn_global_load_lds(
            (const __attribute__((address_space(1))) void*)(Ag + (size_t)row * DIM + kg * 8),
            (__attribute__((address_space(3))) void*)(Abase + (size_t)gr * 8), 16, 0, 0);
        __builtin_amdgcn_global_load_lds(
            (const __attribute__((address_space(1))) void*)(Bg + (size_t)row * DIM + kg * 8),
            (__attribute__((address_space(3))) void*)(Bbase + (size_t)gr * 8), 16, 0, 0);
    }
}

__device__ __forceinline__ void compute_pair(
        const _Float16* Abase, const _Float16* Bbase,
        f32x4 (&acc)[4][4], int wm, int wn, int lrow, int g) {
    #pragma unroll
    for (int ks = 0; ks < 2; ++ks) {
        const int kg = ks * 4 + g;
        f16x8 af[4], bf_[4];
        #pragma unroll
        for (int tm = 0; tm < 4; ++tm) {
            int row = wm + tm * 16 + lrow;
            af[tm] = *(const f16x8*)&Abase[(row * 8 + (kg ^ (row & 7))) * 8];
        }
        #pragma unroll
        for (int tn = 0; tn < 4; ++tn) {
            int row = wn + tn * 16 + lrow;
            bf_[tn] = *(const f16x8*)&Bbase[(row * 8 + (kg ^ (row & 7))) * 8];
        }
        #pragma unroll
        for (int tm = 0; tm < 4; ++tm)
            #pragma unroll
            for (int tn = 0; tn < 4; ++tn)
                acc[tm][tn] = __builtin_amdgcn_mfma_f32_16x16x32_f16(
                    af[tm], bf_[tn], acc[tm][tn], 0, 0, 0);
    }
}

// ---------------------------------------------------------------------------
// Kernel B: fp16 distance GEMM (K=256, fp32 accum), TRANSPOSED (A=codes so
// argmin runs over C/D rows: 16 in-thread mins + 2 shuffle steps), with
// single-barrier double-buffered staging: stage(p+1); compute(p); barrier.
// The vmcnt(0) drain before each barrier waits on loads issued a full
// compute-phase earlier -> ~free. LDS 64 KB (4 x 16 KB buffers).
__global__ __launch_bounds__(256) void mfma_argmin_kernel(
        const _Float16* __restrict__ Xh, const _Float16* __restrict__ Ch,
        const float* __restrict__ cnorm,
        float* __restrict__ minv_p, int* __restrict__ mini_p) {
    __shared__ __align__(16) _Float16 lds[32768];   // 64 KB: A0 B0 A1 B1

    const int t = threadIdx.x;
    const int wid = t >> 6, lane = t & 63;
    const int tb0 = blockIdx.x * 128;   // token block
    const int cb0 = blockIdx.y * 128;   // code block
    const int wm = (wid >> 1) * 64;     // wave's code offset
    const int wn = (wid & 1) * 64;      // wave's token offset
    const int lrow = lane & 15;
    const int g = lane >> 4;            // quad

    f32x4 acc[4][4];                    // [tm=codes][tn=tokens]
    #pragma unroll
    for (int a = 0; a < 4; ++a)
        #pragma unroll
        for (int b = 0; b < 4; ++b) acc[a][b] = (f32x4)0.0f;

    const _Float16* Ag = Ch + (size_t)cb0 * DIM;   // codes
    const _Float16* Bg = Xh + (size_t)tb0 * DIM;   // tokens

    stage_pair(Ag, Bg, lds, lds + 8192, t);        // phase 0 -> buf0
    __syncthreads();
    #pragma unroll
    for (int p = 0; p < 4; ++p) {
        _Float16* cur = lds + (p & 1) * 16384;
        if (p < 3) {
            _Float16* nxt = lds + ((p + 1) & 1) * 16384;
            stage_pair(Ag + (p + 1) * 64, Bg + (p + 1) * 64, nxt, nxt + 8192, t);
        }
        compute_pair(cur, cur + 8192, acc, wm, wn, lrow, g);
        __syncthreads();
    }

    // ---- epilogue: d = ||c||^2 - 2 c.x ; argmin over this block's 128 codes
    float* cn_lds = (float*)lds;                   // [128]
    float* cmb_v  = (float*)lds + 128;             // [128][2]
    int*   cmb_i  = (int*)((float*)lds + 384);     // [128][2]
    if (t < 128) cn_lds[t] = cnorm[cb0 + t];
    __syncthreads();

    float cn[16];
    #pragma unroll
    for (int tm = 0; tm < 4; ++tm)
        #pragma unroll
        for (int reg = 0; reg < 4; ++reg)
            cn[tm * 4 + reg] = cn_lds[wm + tm * 16 + g * 4 + reg];

    #pragma unroll
    for (int tn = 0; tn < 4; ++tn) {
        float bv = 1e30f; int bi = 0x7fffffff;
        #pragma unroll
        for (int tm = 0; tm < 4; ++tm) {
            #pragma unroll
            for (int reg = 0; reg < 4; ++reg) {
                float d = fmaf(-2.0f, acc[tm][tn][reg], cn[tm * 4 + reg]);
                int code = cb0 + wm + tm * 16 + g * 4 + reg;  // ascending -> strict <
                if (d < bv) { bv = d; bi = code; }
            }
        }
        #pragma unroll
        for (int off = 16; off <= 32; off <<= 1) {  // reduce over the 4 quads
            float ov = __shfl_xor(bv, off);
            int   oi = __shfl_xor(bi, off);
            if (ov < bv || (ov == bv && oi < bi)) { bv = ov; bi = oi; }
        }
        if (g == 0) {
            int tl = wn + tn * 16 + lrow;           // token-local 0..127
            cmb_v[tl * 2 + (wid >> 1)] = bv;
            cmb_i[tl * 2 + (wid >> 1)] = bi;
        }
    }
    __syncthreads();
    if (t < 128) {
        float v0 = cmb_v[t * 2], v1 = cmb_v[t * 2 + 1];
        int   i0 = cmb_i[t * 2], i1 = cmb_i[t * 2 + 1];
        bool tk = (v1 < v0) || (v1 == v0 && i1 < i0);
        minv_p[(size_t)blockIdx.y * NTOK + tb0 + t] = tk ? v1 : v0;
        mini_p[(size_t)blockIdx.y * NTOK + tb0 + t] = tk ? i1 : i0;
    }
}

// ---------------------------------------------------------------------------
// Kernel C: fold the NPB candidates per token (8 threads/token), histogram
// via device atomics, gather codebook rows -> out, per-block loss partial.
__global__ __launch_bounds__(256) void reduce_gather_kernel(
        const float* __restrict__ X, const float* __restrict__ C,
        const float* __restrict__ minv_p, const int* __restrict__ mini_p,
        int* __restrict__ counts, float* __restrict__ out,
        float* __restrict__ psum) {
    __shared__ int   idx_lds[32];
    __shared__ float wsum[4];
    const int m0 = blockIdx.x * 32;
    const int t = threadIdx.x;
    {
        const int tl = t >> 3;          // token-local 0..31
        const int pc = t & 7;           // partial chunk 0..7
        int token = m0 + tl;
        float bv = 1e30f; int bi = 0x7fffffff;
        #pragma unroll
        for (int i = 0; i < 8; ++i) {
            int p = pc * 8 + i;
            float v  = minv_p[(size_t)p * NTOK + token];
            int   ii = mini_p[(size_t)p * NTOK + token];
            if (v < bv || (v == bv && ii < bi)) { bv = v; bi = ii; }
        }
        #pragma unroll
        for (int off = 1; off < 8; off <<= 1) {
            float ov = __shfl_xor(bv, off);
            int   oi = __shfl_xor(bi, off);
            if (ov < bv || (ov == bv && oi < bi)) { bv = ov; bi = oi; }
        }
        if (pc == 0) { idx_lds[tl] = bi; atomicAdd(&counts[bi], 1); }
    }
    __syncthreads();
    const int wid = t >> 6, lane = t & 63;
    float local = 0.0f;
    #pragma unroll
    for (int r = 0; r < 8; ++r) {
        int token = m0 + wid * 8 + r;
        int e = idx_lds[wid * 8 + r];
        float4 q = *(const float4*)&C[(size_t)e * DIM + lane * 4];
        float4 x = *(const float4*)&X[(size_t)token * DIM + lane * 4];
        *(float4*)&out[(size_t)token * DIM + lane * 4] = q;
        float d0 = q.x - x.x, d1 = q.y - x.y, d2 = q.z - x.z, d3 = q.w - x.w;
        local += d0 * d0 + d1 * d1 + d2 * d2 + d3 * d3;
    }
    #pragma unroll
    for (int off = 32; off >= 1; off >>= 1) local += __shfl_xor(local, off);
    if (lane == 0) wsum[wid] = local;
    __syncthreads();
    if (t == 0) psum[blockIdx.x] = wsum[0] + wsum[1] + wsum[2] + wsum[3];
}

// ---------------------------------------------------------------------------
// Kernel D: entropy over the 8192-bin histogram + loss. Single small block.
__global__ __launch_bounds__(256) void finalize_kernel(
        const int* __restrict__ counts, const float* __restrict__ psum,
        float* __restrict__ out) {
    const int t = threadIdx.x;
    double local = 0.0;
    #pragma unroll 1
    for (int e = t; e < NEMB; e += 256) {
        float p = (float)counts[e] * (1.0f / (float)NTOK);
        local += (double)(p * logf(p + 1e-10f));
    }
    float ls = psum[t];          // 256 threads, 256 partial sums
    #pragma unroll
    for (int off = 32; off >= 1; off >>= 1) {
        local += __shfl_xor(local, off);
        ls    += __shfl_xor(ls, off);
    }
    __shared__ double she[4];
    __shared__ float  shs[4];
    int lane = t & 63, wid = t >> 6;
    if (lane == 0) { she[wid] = local; shs[wid] = ls; }
    __syncthreads();
    if (t == 0) {
        double ent = she[0] + she[1] + she[2] + she[3];
        float  ssq = shs[0] + shs[1] + shs[2] + shs[3];
        out[(size_t)NTOK * DIM]     = 1.25f * ssq / (float)((size_t)NTOK * DIM);
        out[(size_t)NTOK * DIM + 1] = expf((float)(-ent));
    }
}

// ---------------------------------------------------------------------------
extern "C" void kernel_launch(void* const* d_in, const int* in_sizes, int n_in,
                              void* d_out, int out_size, void* d_ws, size_t ws_size,
                              hipStream_t stream) {
    const float* X = (const float*)d_in[0];   // [32,256,256] fp32
    const float* C = (const float*)d_in[1];   // [8192,256]   fp32
    float* out = (float*)d_out;

    char* ws = (char*)d_ws;
    size_t o = 0;
    _Float16* Xh = (_Float16*)(ws + o); o += (size_t)NTOK * DIM * 2;
    _Float16* Ch = (_Float16*)(ws + o); o += (size_t)NEMB * DIM * 2;
    float* cnorm  = (float*)(ws + o); o += (size_t)NEMB * 4;
    float* minv_p = (float*)(ws + o); o += (size_t)NPB * NTOK * 4;
    int*   mini_p = (int*)  (ws + o); o += (size_t)NPB * NTOK * 4;
    int*   counts = (int*)  (ws + o); o += (size_t)NEMB * 4;
    float* psum   = (float*)(ws + o);

    convert_kernel<<<dim3(NTOK * DIM / 4 / 256, 2), 256, 0, stream>>>(
        X, C, Xh, Ch, cnorm, counts);
    mfma_argmin_kernel<<<dim3(NTOK / 128, NEMB / 128), 256, 0, stream>>>(
        Xh, Ch, cnorm, minv_p, mini_p);
    reduce_gather_kernel<<<256, 256, 0, stream>>>(
        X, C, minv_p, mini_p, counts, out, psum);
    finalize_kernel<<<1, 256, 0, stream>>>(counts, psum, out);
}